// Round 1
// baseline (1905.201 us; speedup 1.0000x reference)
//
#include <hip/hip_runtime.h>
#include <cstdint>
#include <cstddef>

// Problem constants
#define NE      8192        // num embeddings
#define DIM     256         // embedding dim
#define NPOS    8192        // 2*4*32*32 positions
#define ZELEMS  2097152     // 2*256*4096 elements of z
#define NSTRIDE 1048576     // elements per batch-n in z (256*4096)
#define SPATIAL 4096        // 4*32*32

// Kernel-2 tiling
#define POS_PER_BLK 64
#define ESPLIT      4
#define EBLK        (NE / ESPLIT)      // 2048 embeddings per block
#define K2_THREADS  256
#define K2_WAVES    4
#define EPT         (EBLK / K2_WAVES)  // 512 embeddings per thread

// ---------------------------------------------------------------------------
// K1: norms[e] = sum_d w[e][d]^2   (one wave per embedding)
// ---------------------------------------------------------------------------
__global__ void vq_norms(const float* __restrict__ w, float* __restrict__ norms) {
    int e    = blockIdx.x * 4 + (threadIdx.x >> 6);
    int lane = threadIdx.x & 63;
    const float4 v = *(const float4*)(w + (size_t)e * DIM + lane * 4);
    float s = v.x * v.x + v.y * v.y + v.z * v.z + v.w * v.w;
    #pragma unroll
    for (int off = 32; off; off >>= 1) s += __shfl_down(s, off);
    if (lane == 0) norms[e] = s;
}

// ---------------------------------------------------------------------------
// K2: fused fp32 GEMM + running argmin.
//   grid = 128 position-tiles * ESPLIT e-splits.
//   z-tile staged in LDS as zt[d][p] (d-major): lane=p -> conflict-free.
//   Each thread: 1 position, EPT embeddings, 8 accumulators at a time.
//   w rows are wave-uniform -> scalar loads (s_load_dwordx4).
//   Result combined across e-splits via u64 atomicMin of (ordfloat<<13)|e.
// ---------------------------------------------------------------------------
__global__ __launch_bounds__(K2_THREADS) void vq_argmin(
        const float* __restrict__ z, const float* __restrict__ w,
        const float* __restrict__ norms,
        unsigned long long* __restrict__ keys) {
    __shared__ float zt[DIM * POS_PER_BLK];   // 64 KB, layout [d][p]

    const int pb  = blockIdx.x >> 2;          // position-tile id (0..127)
    const int es  = blockIdx.x & (ESPLIT - 1);
    const int tid = threadIdx.x;

    const int pbase = pb * POS_PER_BLK;
    const int n     = pbase >> 12;            // 4096 positions per n
    const int sbase = pbase & (SPATIAL - 1);
    const float* zsrc = z + (size_t)n * NSTRIDE + sbase;

    // stage z-tile: consecutive threads -> consecutive p (coalesced global,
    // conflict-free LDS)
    for (int i = tid; i < DIM * POS_PER_BLK; i += K2_THREADS) {
        int d = i >> 6, p = i & 63;
        zt[i] = zsrc[(size_t)d * SPATIAL + p];
    }
    __syncthreads();

    const int p     = tid & 63;
    const int chunk = tid >> 6;               // wave id: e-range uniform per wave
    const int e0    = es * EBLK + chunk * EPT;

    float bestv = 3.0e38f;
    int   beste = 0;

    for (int eg = 0; eg < EPT; eg += 8) {
        const int ebase = __builtin_amdgcn_readfirstlane(e0 + eg);
        const float* wr = w + (size_t)ebase * DIM;
        float acc[8];
        #pragma unroll
        for (int j = 0; j < 8; ++j) acc[j] = 0.0f;

        #pragma unroll 4
        for (int d = 0; d < DIM; d += 4) {
            float z0 = zt[(d + 0) * 64 + p];
            float z1 = zt[(d + 1) * 64 + p];
            float z2 = zt[(d + 2) * 64 + p];
            float z3 = zt[(d + 3) * 64 + p];
            #pragma unroll
            for (int j = 0; j < 8; ++j) {
                const float4 w4 = *(const float4*)(wr + j * DIM + d);
                acc[j] = fmaf(z0, w4.x,
                         fmaf(z1, w4.y,
                         fmaf(z2, w4.z,
                         fmaf(z3, w4.w, acc[j]))));
            }
        }
        #pragma unroll
        for (int j = 0; j < 8; ++j) {
            float score = norms[ebase + j] - 2.0f * acc[j];
            if (score < bestv) { bestv = score; beste = ebase + j; }
        }
    }

    // monotone float->uint map, pack with index (lowest index wins ties)
    unsigned int u = __float_as_uint(bestv);
    u = (u & 0x80000000u) ? ~u : (u | 0x80000000u);
    unsigned long long key = ((unsigned long long)u << 13) | (unsigned)beste;
    atomicMin(&keys[pbase + p], key);
}

// ---------------------------------------------------------------------------
// K3: gather z_q, write straight-through output (mimic ref rounding:
//     out = z_l + (z_q - z_l)), accumulate loss, write float index map.
// ---------------------------------------------------------------------------
__global__ void vq_out(const float* __restrict__ z, const float* __restrict__ w,
                       const unsigned long long* __restrict__ keys,
                       float* __restrict__ out, float* __restrict__ lossacc) {
    int gi = blockIdx.x * 256 + threadIdx.x;     // one element of z each
    int n  = gi >> 20;                           // NSTRIDE = 2^20
    int r  = gi & (NSTRIDE - 1);
    int d  = r >> 12;                            // SPATIAL = 2^12
    int s  = r & (SPATIAL - 1);
    int p  = (n << 12) | s;

    int   e  = (int)(keys[p] & 8191ull);
    float zl = z[gi];
    float zq = w[(size_t)e * DIM + d];
    out[gi] = zl + (zq - zl);                    // straight-through value

    float diff = zq - zl;
    float ls   = diff * diff;
    #pragma unroll
    for (int off = 32; off; off >>= 1) ls += __shfl_down(ls, off);
    if ((threadIdx.x & 63) == 0) atomicAdd(lossacc, ls);

    if (gi < NPOS) {
        int ei = (int)(keys[gi] & 8191ull);
        out[ZELEMS + 1 + gi] = (float)ei;        // index output as float
    }
}

__global__ void vq_loss_final(const float* __restrict__ lossacc,
                              float* __restrict__ out) {
    // loss = mean + BETA*mean of identical squared diffs = 1.25 * mean
    out[ZELEMS] = 1.25f * lossacc[0] / (float)ZELEMS;
}

// ---------------------------------------------------------------------------
extern "C" void kernel_launch(void* const* d_in, const int* in_sizes, int n_in,
                              void* d_out, int out_size, void* d_ws, size_t ws_size,
                              hipStream_t stream) {
    const float* z = (const float*)d_in[0];   // [2,256,4,32,32] fp32
    const float* w = (const float*)d_in[1];   // [8192,256] fp32
    float* out = (float*)d_out;               // [z_q | loss | index] fp32

    float*              norms   = (float*)d_ws;                          // 32 KB
    unsigned long long* keys    = (unsigned long long*)((char*)d_ws + 32768); // 64 KB
    float*              lossacc = (float*)((char*)d_ws + 32768 + 65536);

    hipMemsetAsync(keys, 0xFF, NPOS * sizeof(unsigned long long), stream);
    hipMemsetAsync(lossacc, 0, sizeof(float), stream);

    vq_norms <<<NE / 4, 256, 0, stream>>>(w, norms);
    vq_argmin<<<(NPOS / POS_PER_BLK) * ESPLIT, K2_THREADS, 0, stream>>>(z, w, norms, keys);
    vq_out   <<<ZELEMS / 256, 256, 0, stream>>>(z, w, keys, out, lossacc);
    vq_loss_final<<<1, 1, 0, stream>>>(lossacc, out);
}

// Round 6
// 557.056 us; speedup vs baseline: 3.4201x; 3.4201x over previous
//
#include <hip/hip_runtime.h>
#include <cstdint>
#include <cstddef>

// Problem constants
#define NE      8192
#define DIM     256
#define NPOS    8192        // 2*4*32*32
#define ZELEMS  2097152     // 2*256*4096
#define NSTRIDE 1048576     // per-batch elements of z
#define SPATIAL 4096

// Packed-operand geometry: rows of 576 halfs = [hi(256) | lo(256) | slot(64)]
// GEMM K-schedule (13 steps of 64) reads: zh*wh (0-3), zl*wh (4-7),
// zh*wl (8-11), ones*norm (12)  -> full double-fp16 product, err ~2e-5 scaled.
#define KTOT    576
#define KSTEP   64
#define NSTEPS  13
#define ROWB    1152        // KTOT * 2 bytes
#define ES      8           // e-splits (1024 e each)
#define PBLK    256         // positions per block

typedef _Float16 half8 __attribute__((ext_vector_type(8)));
typedef float    f32x4 __attribute__((ext_vector_type(4)));

__device__ __forceinline__ unsigned ordmap(float f) {
    unsigned u = __float_as_uint(f);
    return u ^ (unsigned)(((int)u >> 31) | 0x80000000);
}
__device__ __forceinline__ float unord(unsigned long long k) {
    unsigned v = (unsigned)(k >> 13);
    unsigned u = (v & 0x80000000u) ? (v ^ 0x80000000u) : ~v;
    return __uint_as_float(u);
}

// ---------------------------------------------------------------------------
// conv_z: z[n][d][s] -> A_packed[pos][576] = [hi(-2z) | lo(-2z) | 1,1,0...]
// ---------------------------------------------------------------------------
__global__ void conv_z(const float* __restrict__ z, _Float16* __restrict__ Apk) {
    __shared__ float zt[256 * 64];
    const int tid = threadIdx.x;
    const int pbase = blockIdx.x * 64;
    const int n = pbase >> 12;
    const int sbase = pbase & (SPATIAL - 1);
    const float* zsrc = z + (size_t)n * NSTRIDE + sbase;
    for (int i = tid; i < 256 * 64; i += 256) {
        int d = i >> 6, p = i & 63;
        zt[i] = zsrc[(size_t)d * SPATIAL + p];
    }
    __syncthreads();
    const int p = tid & 63, seg = tid >> 6;
    _Float16* rowp = Apk + (size_t)(pbase + p) * KTOT;
    for (int j8 = 0; j8 < 8; ++j8) {
        half8 hv, lv;
        #pragma unroll
        for (int jj = 0; jj < 8; ++jj) {
            int d = seg * 64 + j8 * 8 + jj;
            float v = -2.0f * zt[d * 64 + p];
            _Float16 h = (_Float16)v;
            hv[jj] = h;
            lv[jj] = (_Float16)(v - (float)h);
        }
        *(half8*)(rowp + seg * 64 + j8 * 8) = hv;
        *(half8*)(rowp + 256 + seg * 64 + j8 * 8) = lv;
    }
    if (tid < 64) {
        _Float16* r2 = Apk + (size_t)(pbase + tid) * KTOT + 512;
        #pragma unroll
        for (int q = 0; q < 8; ++q) {
            half8 v8;
            #pragma unroll
            for (int jj = 0; jj < 8; ++jj) v8[jj] = (_Float16)0.0f;
            if (q == 0) { v8[0] = (_Float16)1.0f; v8[1] = (_Float16)1.0f; }
            *(half8*)(r2 + q * 8) = v8;
        }
    }
}

// ---------------------------------------------------------------------------
// conv_w: w[e][d] -> B_packed[e][576] = [hi(8192w) | lo | nh,nl,0...]
//   n = 8192*||w||^2 split hi/lo (slots 512,513 pair with A's 1,1)
// ---------------------------------------------------------------------------
__global__ void conv_w(const float* __restrict__ w, _Float16* __restrict__ Bpk) {
    __shared__ float red[4];
    const int e = blockIdx.x, t = threadIdx.x;
    float v = w[(size_t)e * DIM + t];
    float vs = v * 8192.0f;
    _Float16 h = (_Float16)vs;
    _Float16 l = (_Float16)(vs - (float)h);
    _Float16* row = Bpk + (size_t)e * KTOT;
    row[t] = h;
    row[256 + t] = l;
    float sq = v * v;
    #pragma unroll
    for (int off = 32; off; off >>= 1) sq += __shfl_down(sq, off);
    if ((t & 63) == 0) red[t >> 6] = sq;
    __syncthreads();
    if (t == 0) {
        float nrm = 8192.0f * (red[0] + red[1] + red[2] + red[3]);
        _Float16 nh = (_Float16)nrm;
        row[512] = nh;
        row[513] = (_Float16)(nrm - (float)nh);
    }
    if (t >= 2 && t < 64) row[512 + t] = (_Float16)0.0f;
}

// ---------------------------------------------------------------------------
// vq_gemm: scaled score C[e][pos] with fused per-position argmin (+2nd best).
// 256 blocks = 32 pos-tiles x 8 e-splits; 8 waves; wave tile 128e x 64pos;
// K-step 64 double-buffered; 16B-chunk XOR swizzle via pre-swizzled source.
// ---------------------------------------------------------------------------
__global__ __launch_bounds__(512, 2) void vq_gemm(
        const _Float16* __restrict__ Apk, const _Float16* __restrict__ Bpk,
        unsigned long long* __restrict__ parts) {
    __shared__ _Float16 Asl[2][PBLK * KSTEP];
    __shared__ _Float16 Bsl[2][256 * KSTEP];

    const int tid = threadIdx.x;
    const int lane = tid & 63;
    const int wid = tid >> 6;
    const int wm = wid >> 2, wn = wid & 3;
    const int es = blockIdx.x & 7, pt = blockIdx.x >> 3;
    const int l15 = lane & 15, l4 = lane >> 4, l7 = lane & 7;
    const int co0 = (l4 ^ l7) << 4;
    const int co1 = ((4 + l4) ^ l7) << 4;
    const int aoff = (wm * 128 + l15) * 128;   // into Bsl (e rows)
    const int boff = (wn * 64 + l15) * 128;    // into Asl (pos rows)

    const int srow = tid >> 3;
    const int schunk = tid & 7;
    const int sw = ((schunk ^ (srow & 7)) << 4);

    const char* Ag = (const char*)(Apk + (size_t)pt * PBLK * KTOT);
    const char* Bg0 = (const char*)(Bpk + (size_t)es * 1024 * KTOT);

    // per-step source 64-half slot within each row
    const int AKT[NSTEPS] = {0,1,2,3, 4,5,6,7, 0,1,2,3, 8};
    const int BKT[NSTEPS] = {0,1,2,3, 0,1,2,3, 4,5,6,7, 8};

#define STAGE(gbase, lbase, ktv) {                                          \
        _Pragma("unroll")                                                   \
        for (int i_ = 0; i_ < 4; ++i_) {                                    \
            int r_ = srow + i_ * 64;                                        \
            const char* g_ = (gbase) + (size_t)r_ * ROWB + (ktv) * 128 + sw;\
            char* lp_ = (char*)(lbase) + r_ * 128 + schunk * 16;            \
            __builtin_amdgcn_global_load_lds(                               \
                (const __attribute__((address_space(1))) void*)g_,          \
                (__attribute__((address_space(3))) void*)lp_, 16, 0, 0);    \
        } }

    float b1[4], b2[4]; int e1[4];
    #pragma unroll
    for (int q = 0; q < 4; ++q) { b1[q] = 3.0e38f; b2[q] = 3.0e38f; e1[q] = 0; }

    for (int st = 0; st < 4; ++st) {
        const char* Bg = Bg0 + (size_t)st * 256 * ROWB;
        STAGE(Ag, Asl[0], 0);
        STAGE(Bg, Bsl[0], 0);
        __syncthreads();

        f32x4 acc[8][4];
        #pragma unroll
        for (int mi = 0; mi < 8; ++mi)
            #pragma unroll
            for (int ni = 0; ni < 4; ++ni) acc[mi][ni] = (f32x4)0.0f;

        #pragma unroll
        for (int kt = 0; kt < NSTEPS; ++kt) {
            const int cb = kt & 1;
            if (kt < NSTEPS - 1) {
                STAGE(Ag, Asl[cb ^ 1], AKT[kt + 1]);
                STAGE(Bg, Bsl[cb ^ 1], BKT[kt + 1]);
            }
            const char* Ab = (const char*)Asl[cb];
            const char* Bb = (const char*)Bsl[cb];
            #pragma unroll
            for (int kb = 0; kb < 2; ++kb) {
                const int co = kb ? co1 : co0;
                half8 af[8], bf[4];
                #pragma unroll
                for (int mi = 0; mi < 8; ++mi)
                    af[mi] = *(const half8*)(Bb + aoff + mi * 2048 + co);
                #pragma unroll
                for (int ni = 0; ni < 4; ++ni)
                    bf[ni] = *(const half8*)(Ab + boff + ni * 2048 + co);
                #pragma unroll
                for (int mi = 0; mi < 8; ++mi)
                    #pragma unroll
                    for (int ni = 0; ni < 4; ++ni)
                        acc[mi][ni] = __builtin_amdgcn_mfma_f32_16x16x32_f16(
                            af[mi], bf[ni], acc[mi][ni], 0, 0, 0);
            }
            __syncthreads();
        }

        const int ebl = es * 1024 + st * 256 + wm * 128 + (l4 << 2);
        #pragma unroll
        for (int mi = 0; mi < 8; ++mi)
            #pragma unroll
            for (int ni = 0; ni < 4; ++ni)
                #pragma unroll
                for (int r = 0; r < 4; ++r) {
                    float v = acc[mi][ni][r];
                    int e = ebl + mi * 16 + r;
                    bool c = v < b1[ni];
                    b2[ni] = fminf(b2[ni], fmaxf(v, b1[ni]));
                    b1[ni] = c ? v : b1[ni];
                    e1[ni] = c ? e : e1[ni];
                }
    }

    #pragma unroll
    for (int ni = 0; ni < 4; ++ni) {
        unsigned long long k1 =
            (((unsigned long long)ordmap(b1[ni])) << 13) | (unsigned)e1[ni];
        unsigned long long k2 = ((unsigned long long)ordmap(b2[ni])) << 13;
        #pragma unroll
        for (int m = 16; m <= 32; m <<= 1) {
            unsigned long long o1 = __shfl_xor(k1, m, 64);
            unsigned long long o2 = __shfl_xor(k2, m, 64);
            unsigned long long mx = k1 > o1 ? k1 : o1;
            k1 = k1 < o1 ? k1 : o1;
            k2 = k2 < o2 ? k2 : o2;
            k2 = k2 < mx ? k2 : mx;
        }
        if (lane < 16) {
            int pos = pt * PBLK + wn * 64 + ni * 16 + l15;
            unsigned long long* pp = parts + (((size_t)(wm * 8 + es)) * NPOS + pos) * 2;
            pp[0] = k1; pp[1] = k2;
        }
    }
#undef STAGE
}

// ---------------------------------------------------------------------------
// combine: merge 16 (best, 2nd) pairs; flag gaps < 0.05 (SCALED units;
// ~2000x the 2e-5 scaled score-error bound) for exact recheck.
// ---------------------------------------------------------------------------
__global__ void vq_combine(const unsigned long long* __restrict__ parts,
                           unsigned long long* __restrict__ keys,
                           int* __restrict__ count, int* __restrict__ list) {
    int pos = blockIdx.x * 256 + threadIdx.x;
    unsigned long long g1 = ~0ull, g2 = ~0ull;
    for (int s = 0; s < 16; ++s) {
        const unsigned long long* pp = parts + (((size_t)s) * NPOS + pos) * 2;
        unsigned long long a1 = pp[0], a2 = pp[1];
        unsigned long long mx = g1 > a1 ? g1 : a1;
        g1 = g1 < a1 ? g1 : a1;
        g2 = g2 < a2 ? g2 : a2;
        g2 = g2 < mx ? g2 : mx;
    }
    keys[pos] = g1;
    if (unord(g2) - unord(g1) < 0.05f) {
        int ix = atomicAdd(count, 1);
        if (ix < NPOS) list[ix] = pos;
    }
}

// ---------------------------------------------------------------------------
// exact recheck (fp64 accumulate) for flagged positions
// ---------------------------------------------------------------------------
__global__ void vq_exact(const float* __restrict__ z, const float* __restrict__ w,
                         const int* __restrict__ list, const int* __restrict__ count,
                         unsigned long long* __restrict__ keys) {
    __shared__ float zv[256];
    __shared__ unsigned long long wk[4];
    const int t = threadIdx.x;
    int cnt = *count; if (cnt > NPOS) cnt = NPOS;
    for (int i = blockIdx.x; i < cnt; i += gridDim.x) {
        int pos = list[i];
        int n = pos >> 12, s = pos & (SPATIAL - 1);
        zv[t] = z[(size_t)n * NSTRIDE + (size_t)t * SPATIAL + s];
        __syncthreads();
        float bb = 3.0e38f; int be = 0;
        for (int e = t; e < NE; e += 256) {
            const float* wr = w + (size_t)e * DIM;
            double nrm = 0.0, dt = 0.0;
            #pragma unroll 4
            for (int d = 0; d < DIM; d += 4) {
                float4 w4 = *(const float4*)(wr + d);
                nrm += (double)w4.x * w4.x + (double)w4.y * w4.y
                     + (double)w4.z * w4.z + (double)w4.w * w4.w;
                dt  += (double)w4.x * zv[d] + (double)w4.y * zv[d + 1]
                     + (double)w4.z * zv[d + 2] + (double)w4.w * zv[d + 3];
            }
            float sc = (float)(nrm - 2.0 * dt);
            if (sc < bb) { bb = sc; be = e; }
        }
        unsigned long long k = (((unsigned long long)ordmap(bb)) << 13) | (unsigned)be;
        #pragma unroll
        for (int off = 32; off; off >>= 1) {
            unsigned long long o = __shfl_down(k, off, 64);
            k = k < o ? k : o;
        }
        if ((t & 63) == 0) wk[t >> 6] = k;
        __syncthreads();
        if (t == 0) {
            unsigned long long m0 = wk[0] < wk[1] ? wk[0] : wk[1];
            unsigned long long m1 = wk[2] < wk[3] ? wk[2] : wk[3];
            keys[pos] = m0 < m1 ? m0 : m1;
        }
        __syncthreads();
    }
}

// ---------------------------------------------------------------------------
// vq_out: gather z_q, straight-through output, loss partials, index map
// ---------------------------------------------------------------------------
__global__ void vq_out(const float* __restrict__ z, const float* __restrict__ w,
                       const unsigned long long* __restrict__ keys,
                       float* __restrict__ out, float* __restrict__ partial) {
    __shared__ float red[4];
    int gi = blockIdx.x * 256 + threadIdx.x;
    int n = gi >> 20;
    int r = gi & (NSTRIDE - 1);
    int d = r >> 12;
    int s = r & (SPATIAL - 1);
    int p = (n << 12) | s;

    int e = (int)(keys[p] & 8191ull);
    float zl = z[gi];
    float zq = w[(size_t)e * DIM + d];
    out[gi] = zl + (zq - zl);

    float diff = zq - zl;
    float ls = diff * diff;
    #pragma unroll
    for (int off = 32; off; off >>= 1) ls += __shfl_down(ls, off);
    if ((threadIdx.x & 63) == 0) red[threadIdx.x >> 6] = ls;
    __syncthreads();
    if (threadIdx.x == 0) partial[blockIdx.x] = red[0] + red[1] + red[2] + red[3];

    if (gi < NPOS) {
        int ei = (int)(keys[gi] & 8191ull);
        out[ZELEMS + 1 + gi] = (float)ei;
    }
}

__global__ void vq_loss_final(const float* __restrict__ partial, float* __restrict__ out) {
    __shared__ float red[4];
    float sum = 0.f;
    for (int i = threadIdx.x; i < 8192; i += 256) sum += partial[i];
    #pragma unroll
    for (int off = 32; off; off >>= 1) sum += __shfl_down(sum, off);
    if ((threadIdx.x & 63) == 0) red[threadIdx.x >> 6] = sum;
    __syncthreads();
    if (threadIdx.x == 0)
        out[ZELEMS] = 1.25f * (red[0] + red[1] + red[2] + red[3]) / (float)ZELEMS;
}

// ---------------------------------------------------------------------------
extern "C" void kernel_launch(void* const* d_in, const int* in_sizes, int n_in,
                              void* d_out, int out_size, void* d_ws, size_t ws_size,
                              hipStream_t stream) {
    const float* z = (const float*)d_in[0];
    const float* w = (const float*)d_in[1];
    float* out = (float*)d_out;

    char* wsb = (char*)d_ws;
    _Float16* Apk = (_Float16*)(wsb);                                  //  9,437,184
    _Float16* Bpk = (_Float16*)(wsb + 9437184);                        //  9,437,184
    unsigned long long* parts = (unsigned long long*)(wsb + 18874368); //  2,097,152
    unsigned long long* keys  = (unsigned long long*)(wsb + 20971520); //     65,536
    int*   count   = (int*)(wsb + 21037056);                           //          4
    int*   list    = (int*)(wsb + 21037072);                           //     32,768
    float* partial = (float*)(wsb + 21069856);                         //     32,768

    hipMemsetAsync(count, 0, 4, stream);

    conv_z <<<NPOS / 64, 256, 0, stream>>>(z, Apk);
    conv_w <<<NE, 256, 0, stream>>>(w, Bpk);
    vq_gemm<<<(NPOS / PBLK) * ES, 512, 0, stream>>>(Apk, Bpk, parts);
    vq_combine<<<NPOS / 256, 256, 0, stream>>>(parts, keys, count, list);
    vq_exact<<<128, 256, 0, stream>>>(z, w, list, count, keys);
    vq_out <<<ZELEMS / 256, 256, 0, stream>>>(z, w, keys, out, partial);
    vq_loss_final<<<1, 256, 0, stream>>>(partial, out);
}

// Round 7
// 307.903 us; speedup vs baseline: 6.1877x; 1.8092x over previous
//
#include <hip/hip_runtime.h>
#include <cstdint>
#include <cstddef>

// Problem constants
#define NE      8192
#define DIM     256
#define NPOS    8192        // 2*4*32*32
#define ZELEMS  2097152     // 2*256*4096
#define NSTRIDE 1048576     // per-batch elements of z
#define SPATIAL 4096

// Packed-operand geometry: rows of 576 halfs = [hi(256) | lo(256) | slot(64)]
// GEMM K-schedule (9 steps of 64): zh*wh (0-3), zl*wh (4-7), ones*norm (8).
// Dropped zh*wl term -> score error std ~2.2e-3 scaled; flag threshold 0.05
// is ~22 sigma, flagged positions (~50) get exact fp64 recheck.
#define KTOT    576
#define KSTEP   64
#define NSTEPS  9
#define ROWB    1152        // KTOT * 2 bytes
#define ES      8           // e-splits (1024 e each)
#define PBLK    256         // positions per block

typedef _Float16 half8 __attribute__((ext_vector_type(8)));
typedef float    f32x4 __attribute__((ext_vector_type(4)));

__device__ __forceinline__ unsigned ordmap(float f) {
    unsigned u = __float_as_uint(f);
    return u ^ (unsigned)(((int)u >> 31) | 0x80000000);
}
__device__ __forceinline__ float unord(unsigned long long k) {
    unsigned v = (unsigned)(k >> 13);
    unsigned u = (v & 0x80000000u) ? (v ^ 0x80000000u) : ~v;
    return __uint_as_float(u);
}

// ---------------------------------------------------------------------------
// conv_z: z[n][d][s] -> A_packed[pos][576] = [hi(-2z) | lo(-2z) | 1,1,0...]
// ---------------------------------------------------------------------------
__global__ void conv_z(const float* __restrict__ z, _Float16* __restrict__ Apk) {
    __shared__ float zt[256 * 64];
    const int tid = threadIdx.x;
    const int pbase = blockIdx.x * 64;
    const int n = pbase >> 12;
    const int sbase = pbase & (SPATIAL - 1);
    const float* zsrc = z + (size_t)n * NSTRIDE + sbase;
    for (int i = tid; i < 256 * 64; i += 256) {
        int d = i >> 6, p = i & 63;
        zt[i] = zsrc[(size_t)d * SPATIAL + p];
    }
    __syncthreads();
    const int p = tid & 63, seg = tid >> 6;
    _Float16* rowp = Apk + (size_t)(pbase + p) * KTOT;
    for (int j8 = 0; j8 < 8; ++j8) {
        half8 hv, lv;
        #pragma unroll
        for (int jj = 0; jj < 8; ++jj) {
            int d = seg * 64 + j8 * 8 + jj;
            float v = -2.0f * zt[d * 64 + p];
            _Float16 h = (_Float16)v;
            hv[jj] = h;
            lv[jj] = (_Float16)(v - (float)h);
        }
        *(half8*)(rowp + seg * 64 + j8 * 8) = hv;
        *(half8*)(rowp + 256 + seg * 64 + j8 * 8) = lv;
    }
    if (tid < 64) {
        _Float16* r2 = Apk + (size_t)(pbase + tid) * KTOT + 512;
        #pragma unroll
        for (int q = 0; q < 8; ++q) {
            half8 v8;
            #pragma unroll
            for (int jj = 0; jj < 8; ++jj) v8[jj] = (_Float16)0.0f;
            if (q == 0) { v8[0] = (_Float16)1.0f; v8[1] = (_Float16)1.0f; }
            *(half8*)(r2 + q * 8) = v8;
        }
    }
}

// ---------------------------------------------------------------------------
// conv_w: w[e][d] -> B_packed[e][576] = [hi(8192w) | lo | nh,nl,0...]
// (lo half retained in layout but no longer staged by the 9-step schedule)
// ---------------------------------------------------------------------------
__global__ void conv_w(const float* __restrict__ w, _Float16* __restrict__ Bpk) {
    __shared__ float red[4];
    const int e = blockIdx.x, t = threadIdx.x;
    float v = w[(size_t)e * DIM + t];
    float vs = v * 8192.0f;
    _Float16 h = (_Float16)vs;
    _Float16 l = (_Float16)(vs - (float)h);
    _Float16* row = Bpk + (size_t)e * KTOT;
    row[t] = h;
    row[256 + t] = l;
    float sq = v * v;
    #pragma unroll
    for (int off = 32; off; off >>= 1) sq += __shfl_down(sq, off);
    if ((t & 63) == 0) red[t >> 6] = sq;
    __syncthreads();
    if (t == 0) {
        float nrm = 8192.0f * (red[0] + red[1] + red[2] + red[3]);
        _Float16 nh = (_Float16)nrm;
        row[512] = nh;
        row[513] = (_Float16)(nrm - (float)nh);
    }
    if (t >= 2 && t < 64) row[512 + t] = (_Float16)0.0f;
}

// ---------------------------------------------------------------------------
// vq_gemm: scaled score C[e][pos] with fused per-position argmin (+2nd best).
// 256 blocks = 32 pos-tiles x 8 e-splits; 8 waves; wave tile 128e x 64pos;
// K-step 64 double-buffered; 16B-chunk XOR swizzle via pre-swizzled source.
// ---------------------------------------------------------------------------
__global__ __launch_bounds__(512, 2) void vq_gemm(
        const _Float16* __restrict__ Apk, const _Float16* __restrict__ Bpk,
        unsigned long long* __restrict__ parts) {
    __shared__ _Float16 Asl[2][PBLK * KSTEP];
    __shared__ _Float16 Bsl[2][256 * KSTEP];

    const int tid = threadIdx.x;
    const int lane = tid & 63;
    const int wid = tid >> 6;
    const int wm = wid >> 2, wn = wid & 3;
    const int es = blockIdx.x & 7, pt = blockIdx.x >> 3;
    const int l15 = lane & 15, l4 = lane >> 4, l7 = lane & 7;
    const int co0 = (l4 ^ l7) << 4;
    const int co1 = ((4 + l4) ^ l7) << 4;
    const int aoff = (wm * 128 + l15) * 128;   // into Bsl (e rows)
    const int boff = (wn * 64 + l15) * 128;    // into Asl (pos rows)

    const int srow = tid >> 3;
    const int schunk = tid & 7;
    const int sw = ((schunk ^ (srow & 7)) << 4);

    const char* Ag = (const char*)(Apk + (size_t)pt * PBLK * KTOT);
    const char* Bg0 = (const char*)(Bpk + (size_t)es * 1024 * KTOT);

    // per-step source 64-half slot within each row:
    // steps 0-3: zh*wh, 4-7: zl*wh, 8: ones*norm
    const int AKT[NSTEPS] = {0,1,2,3, 4,5,6,7, 8};
    const int BKT[NSTEPS] = {0,1,2,3, 0,1,2,3, 8};

#define STAGE(gbase, lbase, ktv) {                                          \
        _Pragma("unroll")                                                   \
        for (int i_ = 0; i_ < 4; ++i_) {                                    \
            int r_ = srow + i_ * 64;                                        \
            const char* g_ = (gbase) + (size_t)r_ * ROWB + (ktv) * 128 + sw;\
            char* lp_ = (char*)(lbase) + r_ * 128 + schunk * 16;            \
            __builtin_amdgcn_global_load_lds(                               \
                (const __attribute__((address_space(1))) void*)g_,          \
                (__attribute__((address_space(3))) void*)lp_, 16, 0, 0);    \
        } }

    float b1[4], b2[4]; int e1[4];
    #pragma unroll
    for (int q = 0; q < 4; ++q) { b1[q] = 3.0e38f; b2[q] = 3.0e38f; e1[q] = 0; }

    for (int st = 0; st < 4; ++st) {
        const char* Bg = Bg0 + (size_t)st * 256 * ROWB;
        STAGE(Ag, Asl[0], 0);
        STAGE(Bg, Bsl[0], 0);
        __syncthreads();

        f32x4 acc[8][4];
        #pragma unroll
        for (int mi = 0; mi < 8; ++mi)
            #pragma unroll
            for (int ni = 0; ni < 4; ++ni) acc[mi][ni] = (f32x4)0.0f;

        #pragma unroll
        for (int kt = 0; kt < NSTEPS; ++kt) {
            const int cb = kt & 1;
            if (kt < NSTEPS - 1) {
                STAGE(Ag, Asl[cb ^ 1], AKT[kt + 1]);
                STAGE(Bg, Bsl[cb ^ 1], BKT[kt + 1]);
            }
            const char* Ab = (const char*)Asl[cb];
            const char* Bb = (const char*)Bsl[cb];
            #pragma unroll
            for (int kb = 0; kb < 2; ++kb) {
                const int co = kb ? co1 : co0;
                half8 af[8], bf[4];
                #pragma unroll
                for (int mi = 0; mi < 8; ++mi)
                    af[mi] = *(const half8*)(Bb + aoff + mi * 2048 + co);
                #pragma unroll
                for (int ni = 0; ni < 4; ++ni)
                    bf[ni] = *(const half8*)(Ab + boff + ni * 2048 + co);
                #pragma unroll
                for (int mi = 0; mi < 8; ++mi)
                    #pragma unroll
                    for (int ni = 0; ni < 4; ++ni)
                        acc[mi][ni] = __builtin_amdgcn_mfma_f32_16x16x32_f16(
                            af[mi], bf[ni], acc[mi][ni], 0, 0, 0);
            }
            __syncthreads();
        }

        const int ebl = es * 1024 + st * 256 + wm * 128 + (l4 << 2);
        #pragma unroll
        for (int mi = 0; mi < 8; ++mi)
            #pragma unroll
            for (int ni = 0; ni < 4; ++ni)
                #pragma unroll
                for (int r = 0; r < 4; ++r) {
                    float v = acc[mi][ni][r];
                    int e = ebl + mi * 16 + r;
                    bool c = v < b1[ni];
                    b2[ni] = fminf(b2[ni], fmaxf(v, b1[ni]));
                    b1[ni] = c ? v : b1[ni];
                    e1[ni] = c ? e : e1[ni];
                }
    }

    #pragma unroll
    for (int ni = 0; ni < 4; ++ni) {
        unsigned long long k1 =
            (((unsigned long long)ordmap(b1[ni])) << 13) | (unsigned)e1[ni];
        unsigned long long k2 = ((unsigned long long)ordmap(b2[ni])) << 13;
        #pragma unroll
        for (int m = 16; m <= 32; m <<= 1) {
            unsigned long long o1 = __shfl_xor(k1, m, 64);
            unsigned long long o2 = __shfl_xor(k2, m, 64);
            unsigned long long mx = k1 > o1 ? k1 : o1;
            k1 = k1 < o1 ? k1 : o1;
            k2 = k2 < o2 ? k2 : o2;
            k2 = k2 < mx ? k2 : mx;
        }
        if (lane < 16) {
            int pos = pt * PBLK + wn * 64 + ni * 16 + l15;
            unsigned long long* pp = parts + (((size_t)(wm * 8 + es)) * NPOS + pos) * 2;
            pp[0] = k1; pp[1] = k2;
        }
    }
#undef STAGE
}

// ---------------------------------------------------------------------------
// combine: merge 16 (best, 2nd) pairs; flag gaps < 0.05 scaled (~22 sigma of
// the 2.2e-3 dropped-term error) and RESET their key so vq_exact owns it.
// ---------------------------------------------------------------------------
__global__ void vq_combine(const unsigned long long* __restrict__ parts,
                           unsigned long long* __restrict__ keys,
                           int* __restrict__ count, int* __restrict__ list) {
    int pos = blockIdx.x * 256 + threadIdx.x;
    unsigned long long g1 = ~0ull, g2 = ~0ull;
    for (int s = 0; s < 16; ++s) {
        const unsigned long long* pp = parts + (((size_t)s) * NPOS + pos) * 2;
        unsigned long long a1 = pp[0], a2 = pp[1];
        unsigned long long mx = g1 > a1 ? g1 : a1;
        g1 = g1 < a1 ? g1 : a1;
        g2 = g2 < a2 ? g2 : a2;
        g2 = g2 < mx ? g2 : mx;
    }
    if (unord(g2) - unord(g1) < 0.05f) {
        int ix = atomicAdd(count, 1);
        list[ix] = pos;            // list capacity = NPOS, cannot overflow
        keys[pos] = ~0ull;         // exact recheck fully determines this pos
    } else {
        keys[pos] = g1;
    }
}

// ---------------------------------------------------------------------------
// exact recheck (fp64), chunked: work-item = (flagged pos, 256-e chunk).
// 1024-block grid-stride; block-reduce then atomicMin into keys[pos].
// ---------------------------------------------------------------------------
#define NCHUNK 32
__global__ void vq_exact(const float* __restrict__ z, const float* __restrict__ w,
                         const int* __restrict__ list, const int* __restrict__ count,
                         unsigned long long* __restrict__ keys) {
    __shared__ float zv[256];
    __shared__ unsigned long long wk[4];
    const int t = threadIdx.x;
    int cnt = *count; if (cnt > NPOS) cnt = NPOS;
    int nwork = cnt * NCHUNK;
    for (int item = blockIdx.x; item < nwork; item += gridDim.x) {
        int pos = list[item >> 5];
        int c = item & (NCHUNK - 1);
        int n = pos >> 12, s = pos & (SPATIAL - 1);
        zv[t] = z[(size_t)n * NSTRIDE + (size_t)t * SPATIAL + s];
        __syncthreads();

        int e = c * 256 + t;                 // one embedding per thread
        const float* wr = w + (size_t)e * DIM;
        double nrm = 0.0, dt = 0.0;
        #pragma unroll 4
        for (int d = 0; d < DIM; d += 4) {
            float4 w4 = *(const float4*)(wr + d);
            nrm += (double)w4.x * w4.x + (double)w4.y * w4.y
                 + (double)w4.z * w4.z + (double)w4.w * w4.w;
            dt  += (double)w4.x * zv[d] + (double)w4.y * zv[d + 1]
                 + (double)w4.z * zv[d + 2] + (double)w4.w * zv[d + 3];
        }
        // match GEMM scaling (x8192) so keys are comparable across paths
        float sc = (float)(8192.0 * (nrm - 2.0 * dt));
        unsigned long long k = (((unsigned long long)ordmap(sc)) << 13) | (unsigned)e;
        #pragma unroll
        for (int off = 32; off; off >>= 1) {
            unsigned long long o = __shfl_down(k, off, 64);
            k = k < o ? k : o;
        }
        if ((t & 63) == 0) wk[t >> 6] = k;
        __syncthreads();
        if (t == 0) {
            unsigned long long m0 = wk[0] < wk[1] ? wk[0] : wk[1];
            unsigned long long m1 = wk[2] < wk[3] ? wk[2] : wk[3];
            unsigned long long m = m0 < m1 ? m0 : m1;
            atomicMin(&keys[pos], m);
        }
        __syncthreads();
    }
}

// ---------------------------------------------------------------------------
// vq_out: gather z_q, straight-through output, loss partials, index map
// ---------------------------------------------------------------------------
__global__ void vq_out(const float* __restrict__ z, const float* __restrict__ w,
                       const unsigned long long* __restrict__ keys,
                       float* __restrict__ out, float* __restrict__ partial) {
    __shared__ float red[4];
    int gi = blockIdx.x * 256 + threadIdx.x;
    int n = gi >> 20;
    int r = gi & (NSTRIDE - 1);
    int d = r >> 12;
    int s = r & (SPATIAL - 1);
    int p = (n << 12) | s;

    int e = (int)(keys[p] & 8191ull);
    float zl = z[gi];
    float zq = w[(size_t)e * DIM + d];
    out[gi] = zl + (zq - zl);

    float diff = zq - zl;
    float ls = diff * diff;
    #pragma unroll
    for (int off = 32; off; off >>= 1) ls += __shfl_down(ls, off);
    if ((threadIdx.x & 63) == 0) red[threadIdx.x >> 6] = ls;
    __syncthreads();
    if (threadIdx.x == 0) partial[blockIdx.x] = red[0] + red[1] + red[2] + red[3];

    if (gi < NPOS) {
        int ei = (int)(keys[gi] & 8191ull);
        out[ZELEMS + 1 + gi] = (float)ei;
    }
}

__global__ void vq_loss_final(const float* __restrict__ partial, float* __restrict__ out) {
    __shared__ float red[4];
    float sum = 0.f;
    for (int i = threadIdx.x; i < 8192; i += 256) sum += partial[i];
    #pragma unroll
    for (int off = 32; off; off >>= 1) sum += __shfl_down(sum, off);
    if ((threadIdx.x & 63) == 0) red[threadIdx.x >> 6] = sum;
    __syncthreads();
    if (threadIdx.x == 0)
        out[ZELEMS] = 1.25f * (red[0] + red[1] + red[2] + red[3]) / (float)ZELEMS;
}

// ---------------------------------------------------------------------------
extern "C" void kernel_launch(void* const* d_in, const int* in_sizes, int n_in,
                              void* d_out, int out_size, void* d_ws, size_t ws_size,
                              hipStream_t stream) {
    const float* z = (const float*)d_in[0];
    const float* w = (const float*)d_in[1];
    float* out = (float*)d_out;

    char* wsb = (char*)d_ws;
    _Float16* Apk = (_Float16*)(wsb);                                  //  9,437,184
    _Float16* Bpk = (_Float16*)(wsb + 9437184);                        //  9,437,184
    unsigned long long* parts = (unsigned long long*)(wsb + 18874368); //  2,097,152
    unsigned long long* keys  = (unsigned long long*)(wsb + 20971520); //     65,536
    int*   count   = (int*)(wsb + 21037056);                           //          4
    int*   list    = (int*)(wsb + 21037072);                           //     32,768
    float* partial = (float*)(wsb + 21069856);                         //     32,768

    hipMemsetAsync(count, 0, 4, stream);

    conv_z <<<NPOS / 64, 256, 0, stream>>>(z, Apk);
    conv_w <<<NE, 256, 0, stream>>>(w, Bpk);
    vq_gemm<<<(NPOS / PBLK) * ES, 512, 0, stream>>>(Apk, Bpk, parts);
    vq_combine<<<NPOS / 256, 256, 0, stream>>>(parts, keys, count, list);
    vq_exact<<<1024, 256, 0, stream>>>(z, w, list, count, keys);
    vq_out <<<ZELEMS / 256, 256, 0, stream>>>(z, w, keys, out, partial);
    vq_loss_final<<<1, 256, 0, stream>>>(partial, out);
}